// Round 23
// baseline (1561.063 us; speedup 1.0000x reference)
//
#include <hip/hip_runtime.h>

// Viterbi decode (CRF): B=128, T=4096, L=64.
// Outputs: score[B] (f32), path[B][T] (written as float labels).
constexpr int kB = 128;
constexpr int kT = 4096;
constexpr int kL = 64;
constexpr int kSeg = 64;     // number of backtrace segments
constexpr int kSegLen = 64;  // rows per segment (last segment has 63)
constexpr float kNeg = -10000.0f;

typedef float f32x4 __attribute__((ext_vector_type(4)));

#if __has_builtin(__builtin_amdgcn_permlane16_swap)
#define HAS_PL16 1
#else
#define HAS_PL16 0
#endif

// ---------------- K1 fused: fwd (waves 0-3) + psi consumers (waves 4-7) -----
// fwd step = R20's proven 4-wave structure (795us, absmax 0.0): wave w owns
// outputs [16w,16w+16); lane quad splits j in quarters; combines i^32 =
// permlane32_swap, i^16 = permlane16_swap (runtime-verified vs shfl, fallback).
// delta rows live in a 16-deep LDS ring (4KB); NO per-step global delta store
// (R22 measured one extra store/step = +137us). Waves 4-7 consume ring rows
// with >=8-barrier margin before overwrite (row r dies at step r+16) and
// write psi bytes to global. Barrier sequences mirrored exactly:
// 2x syncthreads + (4 + 255*16 + 15) LDS_BAR per wave group.
__device__ __forceinline__ float part4(const float (&tr)[16], const f32x4* dlp) {
  f32x4 v[4];
#pragma unroll
  for (int q = 0; q < 4; ++q) v[q] = dlp[q];   // 4x ds_read_b128
  float m[4];
#pragma unroll
  for (int q = 0; q < 4; ++q) {
    float a0 = tr[4 * q + 0] + v[q].x;
    float a1 = tr[4 * q + 1] + v[q].y;
    float a2 = tr[4 * q + 2] + v[q].z;
    float a3 = tr[4 * q + 3] + v[q].w;
    m[q] = fmaxf(fmaxf(fmaxf(a0, a1), a2), a3);
  }
  float part = fmaxf(fmaxf(fmaxf(m[0], m[1]), m[2]), m[3]);
  auto w2 = __builtin_amdgcn_permlane32_swap(__float_as_uint(part),
                                             __float_as_uint(part), false, false);
  return fmaxf(__uint_as_float(w2[0]), __uint_as_float(w2[1]));  // i ^ 32
}

__device__ __forceinline__ float red_shfl(const float (&tr)[16], const f32x4* dlp) {
  float m1 = part4(tr, dlp);
  return fmaxf(m1, __shfl_xor(m1, 16, 64));   // i ^ 16 via DS pipe
}

#if HAS_PL16
__device__ __forceinline__ float red_pl16(const float (&tr)[16], const f32x4* dlp) {
  float m1 = part4(tr, dlp);
  auto w2 = __builtin_amdgcn_permlane16_swap(__float_as_uint(m1),
                                             __float_as_uint(m1), false, false);
  return fmaxf(__uint_as_float(w2[0]), __uint_as_float(w2[1]));  // i^16 VALU
}
#endif

// psi consumer: first-occurrence argmax over j for one (row, label).
__device__ __forceinline__ void psi_row(const float (&trp)[kL], const float* ringf,
                                        int rt, int b, int label,
                                        unsigned char* __restrict__ psi) {
  if (rt < 0 || rt > kT - 2) return;   // psi rows 0..4094
  const f32x4* rp = reinterpret_cast<const f32x4*>(ringf + (rt & 15) * kL);
  float best = -INFINITY;
  int idx = 0;
#pragma unroll
  for (int qq = 0; qq < 16; ++qq) {
    f32x4 v = rp[qq];
    float c; bool g;
    c = trp[4 * qq + 0] + v.x; g = c > best; best = g ? c : best; idx = g ? 4 * qq + 0 : idx;
    c = trp[4 * qq + 1] + v.y; g = c > best; best = g ? c : best; idx = g ? 4 * qq + 1 : idx;
    c = trp[4 * qq + 2] + v.z; g = c > best; best = g ? c : best; idx = g ? 4 * qq + 2 : idx;
    c = trp[4 * qq + 3] + v.w; g = c > best; best = g ? c : best; idx = g ? 4 * qq + 3 : idx;
  }
  psi[((size_t)rt * kB + b) * kL + label] = (unsigned char)idx;
}

#define LDS_BAR()                                                               \
  {                                                                             \
    asm volatile("s_waitcnt lgkmcnt(0)" ::: "memory");                          \
    __builtin_amdgcn_s_barrier();                                               \
  }
#define BAR4() LDS_BAR() LDS_BAR() LDS_BAR() LDS_BAR()
#define BAR8() BAR4() BAR4()

__global__ __launch_bounds__(512, 1) void fwd_psi_fused(const float* __restrict__ feats,
                                                        const float* __restrict__ trans,
                                                        unsigned char* __restrict__ psi,
                                                        float* __restrict__ dfin) {
  const int tid = threadIdx.x;
  const int wv = tid >> 6;         // wave 0..7
  const int lane = tid & 63;
  const int b = blockIdx.x;

  __shared__ __align__(16) float ring[16][kL];  // delta ring; row r -> slot r%16
  __shared__ int okf;
  float* ringf = &ring[0][0];

  if (tid == 0) okf = 1;
  if (tid < kL) ring[0][tid] = (tid == 62) ? 0.0f : kNeg;  // t=0
  __syncthreads();

  if (wv < 4) {
    // ================= fwd producer waves =================
    const int q = lane >> 4;
    const int li = lane & 15;
    const int o = 16 * wv + li;
    const bool li16 = (lane < 16);
    float tr[16];
#pragma unroll
    for (int k = 0; k < 16; k += 4) {
      float4 v = *reinterpret_cast<const float4*>(trans + o * kL + 16 * q + k);
      tr[k] = v.x; tr[k + 1] = v.y; tr[k + 2] = v.z; tr[k + 3] = v.w;
    }
    const float* bq16f = ringf + 16 * q;
    const float* fpo = feats + (size_t)b * kT * kL + o;

    // ---- verify pl16 vs shfl (2 chained steps, bitwise; writes only slot 1)
    {
      float fA = fpo[64 * 1], fB = fpo[64 * 2];
      float d1 = red_shfl(tr, (const f32x4*)(bq16f + 0 * kL)) + fA;
      if (li16) ringf[1 * kL + o] = d1;
      LDS_BAR();
      float d2 = red_shfl(tr, (const f32x4*)(bq16f + 1 * kL)) + fB;
      LDS_BAR();
#if HAS_PL16
      float p1 = red_pl16(tr, (const f32x4*)(bq16f + 0 * kL)) + fA;
      if (li16) ringf[1 * kL + o] = p1;
      LDS_BAR();
      float p2 = red_pl16(tr, (const f32x4*)(bq16f + 1 * kL)) + fB;
      LDS_BAR();
      bool wok = __all((__float_as_int(p1) == __float_as_int(d1)) &&
                       (__float_as_int(p2) == __float_as_int(d2))) != 0;
      if (!wok && lane == 0) okf = 0;
#else
      (void)d2;
      if (lane == 0) okf = 0;
#endif
      __syncthreads();
    }
    const bool use16 = (okf != 0);

    float dlast = 0.0f;
    // feat regs: rows 1..16
    float f0 = fpo[64 * 1], f1 = fpo[64 * 2], f2 = fpo[64 * 3], f3 = fpo[64 * 4];
    float f4 = fpo[64 * 5], f5 = fpo[64 * 6], f6 = fpo[64 * 7], f7 = fpo[64 * 8];
    float f8 = fpo[64 * 9], f9 = fpo[64 * 10], f10 = fpo[64 * 11], f11 = fpo[64 * 12];
    float f12 = fpo[64 * 13], f13 = fpo[64 * 14], f14 = fpo[64 * 15], f15 = fpo[64 * 16];
    const float* pf = fpo + 64 * 17;

#define FSTEP(FN, RS, WS, FV)                                                   \
    {                                                                           \
      float m2v = FN(tr, (const f32x4*)(bq16f + (RS) * kL));                    \
      dlast = m2v + FV;                                                         \
      if (li16) ringf[(WS) * kL + o] = dlast;                                   \
      LDS_BAR();                                                                \
    }
#define FITER(FN)                                                               \
    {                                                                           \
      FSTEP(FN, 0, 1, f0)   f0 = pf[0];                                         \
      FSTEP(FN, 1, 2, f1)   f1 = pf[64];                                        \
      FSTEP(FN, 2, 3, f2)   f2 = pf[128];                                       \
      FSTEP(FN, 3, 4, f3)   f3 = pf[192];                                       \
      FSTEP(FN, 4, 5, f4)   f4 = pf[256];                                       \
      FSTEP(FN, 5, 6, f5)   f5 = pf[320];                                       \
      FSTEP(FN, 6, 7, f6)   f6 = pf[384];                                       \
      FSTEP(FN, 7, 8, f7)   f7 = pf[448];                                       \
      FSTEP(FN, 8, 9, f8)   f8 = pf[512];                                       \
      FSTEP(FN, 9, 10, f9)  f9 = pf[576];                                       \
      FSTEP(FN, 10, 11, f10) f10 = pf[640];                                     \
      FSTEP(FN, 11, 12, f11) f11 = pf[704];                                     \
      FSTEP(FN, 12, 13, f12) f12 = pf[768];                                     \
      FSTEP(FN, 13, 14, f13) f13 = pf[832];                                     \
      FSTEP(FN, 14, 15, f14) f14 = pf[896];                                     \
      FSTEP(FN, 15, 0, f15)  f15 = pf[(it == 254) ? 896 : 960];                 \
      pf += 1024;                                                               \
    }
#define FEPI(FN)                                                                \
    {                                                                           \
      FSTEP(FN, 0, 1, f0)   FSTEP(FN, 1, 2, f1)   FSTEP(FN, 2, 3, f2)           \
      FSTEP(FN, 3, 4, f3)   FSTEP(FN, 4, 5, f4)   FSTEP(FN, 5, 6, f5)           \
      FSTEP(FN, 6, 7, f6)   FSTEP(FN, 7, 8, f7)   FSTEP(FN, 8, 9, f8)           \
      FSTEP(FN, 9, 10, f9)  FSTEP(FN, 10, 11, f10) FSTEP(FN, 11, 12, f11)       \
      FSTEP(FN, 12, 13, f12) FSTEP(FN, 13, 14, f13) FSTEP(FN, 14, 15, f14)      \
    }

#if HAS_PL16
    if (use16) {
      for (int it = 0; it < 255; ++it) FITER(red_pl16)   // steps t=1..4080
      FEPI(red_pl16)                                     // steps t=4081..4095
    } else
#endif
    {
      for (int it = 0; it < 255; ++it) FITER(red_shfl)
      FEPI(red_shfl)
    }
#undef FEPI
#undef FITER
#undef FSTEP
    if (li16) dfin[(size_t)b * kL + o] = dlast;   // final delta row (t=4095)
  } else {
    // ================= psi consumer waves =================
    const int pw = wv - 4;       // 0..3
    const int label = lane;
    float trp[kL];
#pragma unroll
    for (int k = 0; k < kL; k += 4) {
      float4 v = *reinterpret_cast<const float4*>(trans + label * kL + k);
      trp[k] = v.x; trp[k + 1] = v.y; trp[k + 2] = v.z; trp[k + 3] = v.w;
    }
    // mirror verify barriers
    LDS_BAR() LDS_BAR()
#if HAS_PL16
    LDS_BAR() LDS_BAR()
#endif
    __syncthreads();

#define PSI2(BASE)                                                              \
    {                                                                           \
      psi_row(trp, ringf, (BASE) + 2 * pw, b, label, psi);                      \
      psi_row(trp, ringf, (BASE) + 2 * pw + 1, b, label, psi);                  \
    }
    for (int it = 0; it < 255; ++it) {
      PSI2(16 * it - 7)     // rows 16it-7..16it   (die at steps 16it+9..+16)
      BAR8()
      PSI2(16 * it + 1)     // rows 16it+1..16it+8 (die next iteration)
      BAR8()
    }
    // epilogue: 15 barriers, matching fwd
    PSI2(4073)              // rows 4073..4080 (die at steps 4089..4096)
    BAR8()
    PSI2(4081)              // rows 4081..4088 (written by epi steps 1..8)
    BAR4() LDS_BAR() LDS_BAR() LDS_BAR()
    PSI2(4089)              // rows 4089..4094 (guard excludes 4095/4096)
#undef PSI2
  }
}

// ---------------- K3: segment composition (in-place psi -> M) ----------------
__global__ __launch_bounds__(256) void seg_compose(unsigned char* psiM,
                                                   unsigned char* __restrict__ C) {
  const int lane = threadIdx.x & 63;
  const int w = blockIdx.x * 4 + (threadIdx.x >> 6);
  const int s = w >> 7;
  const int b = w & 127;
  const int tstart = s * kSegLen;
  const int tend = (tstart + kSegLen < kT) ? tstart + kSegLen : kT - 1;  // last seg: 4095
  const size_t stride = (size_t)kB * kL;
  size_t off = ((size_t)(tend - 1) * kB + b) * kL + lane;
  int m = lane;
  int v = psiM[off];
  for (int t = tend - 1; t > tstart; --t) {
    int vn = psiM[off - stride];          // prefetch next row
    m = __shfl(v, m, 64);                 // m = psi_row[m]
    psiM[off] = (unsigned char)m;         // M[t][b][e] = path[t] | hyp e
    v = vn;
    off -= stride;
  }
  m = __shfl(v, m, 64);
  psiM[off] = (unsigned char)m;
  C[((size_t)s * kB + b) * kL + lane] = (unsigned char)m;  // composed map
}

// ---------------- K4: score, last label, boundary-label scan ----------------
__global__ __launch_bounds__(64) void score_scan(const float* __restrict__ dfin,
                                                 const unsigned char* __restrict__ C,
                                                 int* __restrict__ E,
                                                 float* __restrict__ out) {
  const int b = blockIdx.x;
  const int i = threadIdx.x;
  float d = dfin[(size_t)b * kL + i];
  float m = d;
#pragma unroll
  for (int off = 32; off; off >>= 1) m = fmaxf(m, __shfl_xor(m, off, 64));
  unsigned long long msk = __ballot(d == m);
  int ll = __ffsll(msk) - 1;  // first (lowest) argmax lane
  if (i == 0) {
    out[b] = m;
    out[kB + (size_t)b * kT + (kT - 1)] = (float)ll;
    int lbl = ll;
    for (int s = kSeg - 1; s >= 0; --s) {
      E[s * kB + b] = lbl;                              // label at t_end(s)
      lbl = C[((size_t)s * kB + b) * kL + lbl];         // -> label at t_start(s)
    }
  }
}

// ---------------- K5: parallel path gather ----------------
__global__ __launch_bounds__(256) void path_fill(const unsigned char* __restrict__ M,
                                                 const int* __restrict__ E,
                                                 float* __restrict__ out) {
  const int n = blockIdx.x * 256 + threadIdx.x;  // n = b*4096 + t
  const int b = n >> 12;
  const int t = n & (kT - 1);
  if (t == kT - 1) return;  // written by score_scan
  const int e = E[(t >> 6) * kB + b];
  const unsigned char lab = M[((size_t)t * kB + b) * kL + e];
  out[kB + (size_t)b * kT + t] = (float)lab;
}

extern "C" void kernel_launch(void* const* d_in, const int* in_sizes, int n_in,
                              void* d_out, int out_size, void* d_ws, size_t ws_size,
                              hipStream_t stream) {
  const float* feats = (const float*)d_in[0];
  const float* trans = (const float*)d_in[1];
  float* out = (float*)d_out;
  char* ws = (char*)d_ws;

  const size_t psiB = (size_t)kT * kB * kL;       // 33,554,432
  const size_t CBy  = (size_t)kSeg * kB * kL;     //    524,288
  const size_t EBy  = (size_t)kSeg * kB * 4;      //     32,768

  unsigned char* psi = (unsigned char*)ws;
  unsigned char* C = (unsigned char*)(ws + psiB);
  int* E = (int*)(ws + psiB + CBy);
  float* dfin = (float*)(ws + psiB + CBy + EBy);

  hipLaunchKernelGGL(fwd_psi_fused, dim3(kB), dim3(512), 0, stream,
                     feats, trans, psi, dfin);
  hipLaunchKernelGGL(seg_compose, dim3(2048), dim3(256), 0, stream, psi, C);
  hipLaunchKernelGGL(score_scan, dim3(kB), dim3(64), 0, stream, dfin, C, E, out);
  hipLaunchKernelGGL(path_fill, dim3(2048), dim3(256), 0, stream, psi, E, out);
}

// Round 24
// 1044.346 us; speedup vs baseline: 1.4948x; 1.4948x over previous
//
#include <hip/hip_runtime.h>

// Viterbi decode (CRF): B=128, T=4096, L=64.
// Outputs: score[B] (f32), path[B][T] (written as float labels).
constexpr int kB = 128;
constexpr int kT = 4096;
constexpr int kL = 64;
constexpr int kSeg = 64;     // number of backtrace segments
constexpr int kSegLen = 64;  // rows per segment (last segment has 63)
constexpr float kNeg = -10000.0f;

typedef float f32x4 __attribute__((ext_vector_type(4)));

#if __has_builtin(__builtin_amdgcn_permlane16_swap)
#define HAS_PL16 1
#else
#define HAS_PL16 0
#endif

// ---------------- K1 forward: 4-wave cooperative step (R20, proven 795us) ---
// Block = 256 threads (4 waves); wave w owns outputs [16w,16w+16); lane quad
// (li, li+16, li+32, li+48) splits j into quarters. Per lane: 4 ds_read_b128
// + 16 adds + tree -> quarter-partial. Combines:
//   i^32: (a,b)=permlane32_swap(p,p); fmaxf(a,b) — proven exact (R16-R22).
//   i^16: (a,b)=permlane16_swap(m,m); fmaxf(a,b) — proven exact (R20-R22).
// pl16 verified at runtime (2 chained steps, bitwise, block-uniform flag)
// vs the shfl step; fallback runs the shfl loop. Verify leaves no state.
// Wave-split curve measured: 2w=938, 4w=795, 8w=872; fused psi=1550;
// +1 store/step=+137us — 4-wave with no extra stores is the optimum.
__device__ __forceinline__ float part4(const float (&tr)[16], const f32x4* dlp) {
  f32x4 v[4];
#pragma unroll
  for (int q = 0; q < 4; ++q) v[q] = dlp[q];   // 4x ds_read_b128
  float m[4];
#pragma unroll
  for (int q = 0; q < 4; ++q) {
    float a0 = tr[4 * q + 0] + v[q].x;
    float a1 = tr[4 * q + 1] + v[q].y;
    float a2 = tr[4 * q + 2] + v[q].z;
    float a3 = tr[4 * q + 3] + v[q].w;
    m[q] = fmaxf(fmaxf(fmaxf(a0, a1), a2), a3);  // v_max3 + v_max
  }
  float part = fmaxf(fmaxf(fmaxf(m[0], m[1]), m[2]), m[3]);
  auto w2 = __builtin_amdgcn_permlane32_swap(__float_as_uint(part),
                                             __float_as_uint(part), false, false);
  return fmaxf(__uint_as_float(w2[0]), __uint_as_float(w2[1]));  // i ^ 32 done
}

__device__ __forceinline__ float step_shfl(const float (&tr)[16], const f32x4* dlp,
                                           float fo) {
  float m1 = part4(tr, dlp);
  return fmaxf(m1, __shfl_xor(m1, 16, 64)) + fo;   // i ^ 16 via DS pipe
}

#if HAS_PL16
__device__ __forceinline__ float step_pl16(const float (&tr)[16], const f32x4* dlp,
                                           float fo) {
  float m1 = part4(tr, dlp);
  auto w2 = __builtin_amdgcn_permlane16_swap(__float_as_uint(m1),
                                             __float_as_uint(m1), false, false);
  return fmaxf(__uint_as_float(w2[0]), __uint_as_float(w2[1])) + fo;  // i^16 VALU
}
#endif

__global__ __launch_bounds__(256, 1) void fwd_delta(const float* __restrict__ feats,
                                                    const float* __restrict__ trans,
                                                    float* __restrict__ delta) {
  const int tid = threadIdx.x;
  const int w = tid >> 6;          // wave 0..3
  const int lane = tid & 63;
  const int q = lane >> 4;         // j-quarter
  const int li = lane & 15;
  const int o = 16 * w + li;       // output label owned by this lane quad
  const int b = blockIdx.x;
  const size_t kBL = (size_t)kB * kL;

  float tr[16];
#pragma unroll
  for (int k = 0; k < 16; k += 4) {
    float4 v = *reinterpret_cast<const float4*>(trans + o * kL + 16 * q + k);
    tr[k] = v.x; tr[k + 1] = v.y; tr[k + 2] = v.z; tr[k + 3] = v.w;
  }

  __shared__ __align__(16) float dbuf[2][kL];
  __shared__ int okf;
  const f32x4* dlp0 = reinterpret_cast<const f32x4*>(&dbuf[0][16 * q]);
  const f32x4* dlp1 = reinterpret_cast<const f32x4*>(&dbuf[1][16 * q]);

  if (tid == 0) okf = 1;
  if (tid < kL) {
    float dd = (tid == 62) ? 0.0f : kNeg;
    dbuf[0][tid] = dd;
    delta[(size_t)b * kL + tid] = dd;
  }
  __syncthreads();

  const float* fpo = feats + (size_t)b * kT * kL + o;
  float* dro = delta + (size_t)b * kL + o;  // store base; step t at dro[off]

  // LDS-only barrier: own DS ops complete, then s_barrier (R18-R22, exact).
#define LDS_BAR()                                                               \
  {                                                                             \
    asm volatile("s_waitcnt lgkmcnt(0)" ::: "memory");                          \
    __builtin_amdgcn_s_barrier();                                               \
  }

  // ---- verify pl16 vs shfl: 2 chained steps, bitwise; state-free ----
  {
    float fA = fpo[64 * 1], fB = fpo[64 * 2];
    float d1 = step_shfl(tr, dlp0, fA);
    if (lane < 16) dbuf[1][o] = d1;
    LDS_BAR();
    float d2 = step_shfl(tr, dlp1, fB);
    LDS_BAR();  // all reads of dbuf[1] complete before the pl16 trial rewrites
#if HAS_PL16
    float p1 = step_pl16(tr, dlp0, fA);
    if (lane < 16) dbuf[1][o] = p1;
    LDS_BAR();
    float p2 = step_pl16(tr, dlp1, fB);
    LDS_BAR();
    bool wok = __all((__float_as_int(p1) == __float_as_int(d1)) &&
                     (__float_as_int(p2) == __float_as_int(d2))) != 0;
    if (!wok && lane == 0) okf = 0;
#else
    (void)d2;
    if (lane == 0) okf = 0;
#endif
    __syncthreads();
  }
  const bool use16 = (okf != 0);

  // ---- main loop: EXACT R18/R20 structure (in-bounds proven) ----
  // dbuf[0] still holds t=0 (verify wrote only dbuf[1]).
  float f0 = fpo[64 * 1], f1 = fpo[64 * 2], f2 = fpo[64 * 3], f3 = fpo[64 * 4];
  const float* pf = fpo + 64 * 5;
  size_t off = kBL;  // t=1

#define STEP(FN, DLP, WBUF, FV)                                                 \
  {                                                                             \
    float dnew = FN(tr, DLP, FV);                                               \
    if (lane < 16) {                                                            \
      dbuf[WBUF][o] = dnew;                                                     \
      dro[off] = dnew;                                                          \
    }                                                                           \
    off += kBL;                                                                 \
    LDS_BAR();                                                                  \
  }

#if HAS_PL16
  if (use16) {
    for (int it = 0; it < 1022; ++it) {  // steps t=1..4088
      STEP(step_pl16, dlp0, 1, f0) f0 = pf[0];
      STEP(step_pl16, dlp1, 0, f1) f1 = pf[64];
      STEP(step_pl16, dlp0, 1, f2) f2 = pf[128];
      STEP(step_pl16, dlp1, 0, f3) f3 = pf[192];
      pf += 256;
    }
    float g0 = pf[0], g1 = pf[64], g2 = pf[128];  // rows 4093..4095
    STEP(step_pl16, dlp0, 1, f0)   // 4089
    STEP(step_pl16, dlp1, 0, f1)   // 4090
    STEP(step_pl16, dlp0, 1, f2)   // 4091
    STEP(step_pl16, dlp1, 0, f3)   // 4092
    STEP(step_pl16, dlp0, 1, g0)   // 4093
    STEP(step_pl16, dlp1, 0, g1)   // 4094
    STEP(step_pl16, dlp0, 1, g2)   // 4095
  } else
#endif
  {
    for (int it = 0; it < 1022; ++it) {
      STEP(step_shfl, dlp0, 1, f0) f0 = pf[0];
      STEP(step_shfl, dlp1, 0, f1) f1 = pf[64];
      STEP(step_shfl, dlp0, 1, f2) f2 = pf[128];
      STEP(step_shfl, dlp1, 0, f3) f3 = pf[192];
      pf += 256;
    }
    float g0 = pf[0], g1 = pf[64], g2 = pf[128];
    STEP(step_shfl, dlp0, 1, f0)
    STEP(step_shfl, dlp1, 0, f1)
    STEP(step_shfl, dlp0, 1, f2)
    STEP(step_shfl, dlp1, 0, f3)
    STEP(step_shfl, dlp0, 1, g0)
    STEP(step_shfl, dlp1, 0, g1)
    STEP(step_shfl, dlp0, 1, g2)
  }
#undef STEP
#undef LDS_BAR
}

// ---------------- K2: two-pass backpointers from stored delta ---------------
// Pass 1: 64 sums s[j] = tr[i][j] + delta[r][j] (identical IEEE adds) + max
// via max3-shaped tree (order-invariant, bitwise == fwd's max). Pass 2:
// descending equality scan -> lowest j with s[j]==best = first-occurrence
// argmax (+-0 ties: equality matches both zeros, lowest j wins — identical
// to the strict-> scan and to jnp.argmax). ~231 VALU/row vs 256 for the
// single-pass cmp/cndmask-x2 scan (psi is pure VALU-bound: 94.5% busy).
__global__ __launch_bounds__(256, 1) void psi_from_delta(const float* __restrict__ delta,
                                                         const float* __restrict__ trans,
                                                         unsigned char* __restrict__ psi) {
  const int lane = threadIdx.x & 63;
  const int w = __builtin_amdgcn_readfirstlane(blockIdx.x * 4 + (threadIdx.x >> 6));
  float tr[kL];
#pragma unroll
  for (int k = 0; k < kL; k += 4) {
    float4 v = *reinterpret_cast<const float4*>(trans + lane * kL + k);
    tr[k] = v.x; tr[k + 1] = v.y; tr[k + 2] = v.z; tr[k + 3] = v.w;
  }
  const int r0 = w * 8;  // 8 rows per wave; grid sized exactly
  for (int rr = 0; rr < 8; ++rr) {
    const int r = r0 + rr;
    const float4* row4 = reinterpret_cast<const float4*>(delta + (size_t)r * kL);
    float s[kL];
    float m[16];
#pragma unroll
    for (int q = 0; q < 16; ++q) {
      float4 dv = row4[q];
      s[4 * q + 0] = tr[4 * q + 0] + dv.x;
      s[4 * q + 1] = tr[4 * q + 1] + dv.y;
      s[4 * q + 2] = tr[4 * q + 2] + dv.z;
      s[4 * q + 3] = tr[4 * q + 3] + dv.w;
      m[q] = fmaxf(fmaxf(fmaxf(s[4 * q + 0], s[4 * q + 1]), s[4 * q + 2]),
                   s[4 * q + 3]);  // v_max3 + v_max
    }
    float g0 = fmaxf(fmaxf(m[0], m[1]), m[2]);      // v_max3 x5
    float g1 = fmaxf(fmaxf(m[3], m[4]), m[5]);
    float g2 = fmaxf(fmaxf(m[6], m[7]), m[8]);
    float g3 = fmaxf(fmaxf(m[9], m[10]), m[11]);
    float g4 = fmaxf(fmaxf(m[12], m[13]), m[14]);
    float h0 = fmaxf(fmaxf(g0, g1), g2);            // v_max3 x2
    float h1 = fmaxf(fmaxf(g3, g4), m[15]);
    const float best = fmaxf(h0, h1);
    int idx = 0;
#pragma unroll
    for (int j = kL - 1; j >= 0; --j) idx = (s[j] == best) ? j : idx;
    psi[(size_t)r * kL + lane] = (unsigned char)idx;
  }
}

// ---------------- K3: segment composition (in-place psi -> M) ----------------
__global__ __launch_bounds__(256) void seg_compose(unsigned char* psiM,
                                                   unsigned char* __restrict__ C) {
  const int lane = threadIdx.x & 63;
  const int w = blockIdx.x * 4 + (threadIdx.x >> 6);
  const int s = w >> 7;
  const int b = w & 127;
  const int tstart = s * kSegLen;
  const int tend = (tstart + kSegLen < kT) ? tstart + kSegLen : kT - 1;  // last seg: 4095
  const size_t stride = (size_t)kB * kL;
  size_t off = ((size_t)(tend - 1) * kB + b) * kL + lane;
  int m = lane;
  int v = psiM[off];
  for (int t = tend - 1; t > tstart; --t) {
    int vn = psiM[off - stride];          // prefetch next row
    m = __shfl(v, m, 64);                 // m = psi_row[m]
    psiM[off] = (unsigned char)m;         // M[t][b][e] = path[t] | hyp e
    v = vn;
    off -= stride;
  }
  m = __shfl(v, m, 64);
  psiM[off] = (unsigned char)m;
  C[((size_t)s * kB + b) * kL + lane] = (unsigned char)m;  // composed map
}

// ---------------- K4: score, last label, boundary-label scan ----------------
__global__ __launch_bounds__(64) void score_scan(const float* __restrict__ dfin,
                                                 const unsigned char* __restrict__ C,
                                                 int* __restrict__ E,
                                                 float* __restrict__ out) {
  const int b = blockIdx.x;
  const int i = threadIdx.x;
  float d = dfin[(size_t)b * kL + i];
  float m = d;
#pragma unroll
  for (int off = 32; off; off >>= 1) m = fmaxf(m, __shfl_xor(m, off, 64));
  unsigned long long msk = __ballot(d == m);
  int ll = __ffsll(msk) - 1;  // first (lowest) argmax lane
  if (i == 0) {
    out[b] = m;
    out[kB + (size_t)b * kT + (kT - 1)] = (float)ll;
    int lbl = ll;
    for (int s = kSeg - 1; s >= 0; --s) {
      E[s * kB + b] = lbl;                              // label at t_end(s)
      lbl = C[((size_t)s * kB + b) * kL + lbl];         // -> label at t_start(s)
    }
  }
}

// ---------------- K5: parallel path gather ----------------
__global__ __launch_bounds__(256) void path_fill(const unsigned char* __restrict__ M,
                                                 const int* __restrict__ E,
                                                 float* __restrict__ out) {
  const int n = blockIdx.x * 256 + threadIdx.x;  // n = b*4096 + t
  const int b = n >> 12;
  const int t = n & (kT - 1);
  if (t == kT - 1) return;  // written by score_scan
  const int e = E[(t >> 6) * kB + b];
  const unsigned char lab = M[((size_t)t * kB + b) * kL + e];
  out[kB + (size_t)b * kT + t] = (float)lab;
}

extern "C" void kernel_launch(void* const* d_in, const int* in_sizes, int n_in,
                              void* d_out, int out_size, void* d_ws, size_t ws_size,
                              hipStream_t stream) {
  const float* feats = (const float*)d_in[0];
  const float* trans = (const float*)d_in[1];
  float* out = (float*)d_out;
  char* ws = (char*)d_ws;

  const size_t deltaB = (size_t)kT * kB * kL * 4;   // 134,217,728
  const size_t psiB   = (size_t)kT * kB * kL;       //  33,554,432
  const size_t CBy    = (size_t)kSeg * kB * kL;     //     524,288

  float* delta = (float*)ws;
  unsigned char* psi = (unsigned char*)(ws + deltaB);
  unsigned char* C = (unsigned char*)(ws + deltaB + psiB);
  int* E = (int*)(ws + deltaB + psiB + CBy);
  hipLaunchKernelGGL(fwd_delta, dim3(kB), dim3(256), 0, stream, feats, trans, delta);
  hipLaunchKernelGGL(psi_from_delta, dim3(16380), dim3(256), 0, stream, delta, trans, psi);
  hipLaunchKernelGGL(seg_compose, dim3(2048), dim3(256), 0, stream, psi, C);
  hipLaunchKernelGGL(score_scan, dim3(kB), dim3(64), 0, stream,
                     delta + (size_t)(kT - 1) * kB * kL, C, E, out);
  hipLaunchKernelGGL(path_fill, dim3(2048), dim3(256), 0, stream, psi, E, out);
}

// Round 25
// 1018.944 us; speedup vs baseline: 1.5320x; 1.0249x over previous
//
#include <hip/hip_runtime.h>

// Viterbi decode (CRF): B=128, T=4096, L=64.
// Outputs: score[B] (f32), path[B][T] (written as float labels).
// FINAL (R25 = exact R20 configuration, measured 1017us, absmax 0.0):
//   fwd_delta: 4-wave cooperative step, permlane32+permlane16 combines, 795us
//   psi_from_delta: single-pass argmax scan (high occupancy), ~216us
//   seg_compose/score_scan/path_fill: ~6us
// Ledger (cy/step): 1-wave 1030/670; bpermute 1410; 2w 550; 4w+shfl 533;
// 4w+pl16 466 (OPT); 8w 512; fused-psi 905; +mx store 545; two-pass psi -27us.
constexpr int kB = 128;
constexpr int kT = 4096;
constexpr int kL = 64;
constexpr int kSeg = 64;     // number of backtrace segments
constexpr int kSegLen = 64;  // rows per segment (last segment has 63)
constexpr float kNeg = -10000.0f;

typedef float f32x4 __attribute__((ext_vector_type(4)));

#if __has_builtin(__builtin_amdgcn_permlane16_swap)
#define HAS_PL16 1
#else
#define HAS_PL16 0
#endif

__device__ __forceinline__ float part4(const float (&tr)[16], const f32x4* dlp) {
  f32x4 v[4];
#pragma unroll
  for (int q = 0; q < 4; ++q) v[q] = dlp[q];   // 4x ds_read_b128
  float m[4];
#pragma unroll
  for (int q = 0; q < 4; ++q) {
    float a0 = tr[4 * q + 0] + v[q].x;
    float a1 = tr[4 * q + 1] + v[q].y;
    float a2 = tr[4 * q + 2] + v[q].z;
    float a3 = tr[4 * q + 3] + v[q].w;
    m[q] = fmaxf(fmaxf(fmaxf(a0, a1), a2), a3);  // v_max3 + v_max
  }
  float part = fmaxf(fmaxf(fmaxf(m[0], m[1]), m[2]), m[3]);
  auto w2 = __builtin_amdgcn_permlane32_swap(__float_as_uint(part),
                                             __float_as_uint(part), false, false);
  return fmaxf(__uint_as_float(w2[0]), __uint_as_float(w2[1]));  // i ^ 32 done
}

__device__ __forceinline__ float step_shfl(const float (&tr)[16], const f32x4* dlp,
                                           float fo) {
  float m1 = part4(tr, dlp);
  return fmaxf(m1, __shfl_xor(m1, 16, 64)) + fo;   // i ^ 16 via DS pipe
}

#if HAS_PL16
__device__ __forceinline__ float step_pl16(const float (&tr)[16], const f32x4* dlp,
                                           float fo) {
  float m1 = part4(tr, dlp);
  auto w2 = __builtin_amdgcn_permlane16_swap(__float_as_uint(m1),
                                             __float_as_uint(m1), false, false);
  return fmaxf(__uint_as_float(w2[0]), __uint_as_float(w2[1])) + fo;  // i^16 VALU
}
#endif

__global__ __launch_bounds__(256, 1) void fwd_delta(const float* __restrict__ feats,
                                                    const float* __restrict__ trans,
                                                    float* __restrict__ delta) {
  const int tid = threadIdx.x;
  const int w = tid >> 6;          // wave 0..3
  const int lane = tid & 63;
  const int q = lane >> 4;         // j-quarter
  const int li = lane & 15;
  const int o = 16 * w + li;       // output label owned by this lane quad
  const int b = blockIdx.x;
  const size_t kBL = (size_t)kB * kL;

  float tr[16];
#pragma unroll
  for (int k = 0; k < 16; k += 4) {
    float4 v = *reinterpret_cast<const float4*>(trans + o * kL + 16 * q + k);
    tr[k] = v.x; tr[k + 1] = v.y; tr[k + 2] = v.z; tr[k + 3] = v.w;
  }

  __shared__ __align__(16) float dbuf[2][kL];
  __shared__ int okf;
  const f32x4* dlp0 = reinterpret_cast<const f32x4*>(&dbuf[0][16 * q]);
  const f32x4* dlp1 = reinterpret_cast<const f32x4*>(&dbuf[1][16 * q]);

  if (tid == 0) okf = 1;
  if (tid < kL) {
    float dd = (tid == 62) ? 0.0f : kNeg;
    dbuf[0][tid] = dd;
    delta[(size_t)b * kL + tid] = dd;
  }
  __syncthreads();

  const float* fpo = feats + (size_t)b * kT * kL + o;
  float* dro = delta + (size_t)b * kL + o;  // store base; step t at dro[off]

  // LDS-only barrier: own DS ops complete, then s_barrier (no vmcnt drain).
#define LDS_BAR()                                                               \
  {                                                                             \
    asm volatile("s_waitcnt lgkmcnt(0)" ::: "memory");                          \
    __builtin_amdgcn_s_barrier();                                               \
  }

  // ---- verify pl16 vs shfl: 2 chained steps, bitwise; state-free ----
  {
    float fA = fpo[64 * 1], fB = fpo[64 * 2];
    float d1 = step_shfl(tr, dlp0, fA);
    if (lane < 16) dbuf[1][o] = d1;
    LDS_BAR();
    float d2 = step_shfl(tr, dlp1, fB);
    LDS_BAR();  // all reads of dbuf[1] complete before the pl16 trial rewrites
#if HAS_PL16
    float p1 = step_pl16(tr, dlp0, fA);
    if (lane < 16) dbuf[1][o] = p1;
    LDS_BAR();
    float p2 = step_pl16(tr, dlp1, fB);
    LDS_BAR();
    bool wok = __all((__float_as_int(p1) == __float_as_int(d1)) &&
                     (__float_as_int(p2) == __float_as_int(d2))) != 0;
    if (!wok && lane == 0) okf = 0;
#else
    (void)d2;
    if (lane == 0) okf = 0;
#endif
    __syncthreads();
  }
  const bool use16 = (okf != 0);

  // ---- main loop (in-bounds proven structure) ----
  // dbuf[0] still holds t=0 (verify wrote only dbuf[1]).
  float f0 = fpo[64 * 1], f1 = fpo[64 * 2], f2 = fpo[64 * 3], f3 = fpo[64 * 4];
  const float* pf = fpo + 64 * 5;
  size_t off = kBL;  // t=1

#define STEP(FN, DLP, WBUF, FV)                                                 \
  {                                                                             \
    float dnew = FN(tr, DLP, FV);                                               \
    if (lane < 16) {                                                            \
      dbuf[WBUF][o] = dnew;                                                     \
      dro[off] = dnew;                                                          \
    }                                                                           \
    off += kBL;                                                                 \
    LDS_BAR();                                                                  \
  }

#if HAS_PL16
  if (use16) {
    for (int it = 0; it < 1022; ++it) {  // steps t=1..4088
      STEP(step_pl16, dlp0, 1, f0) f0 = pf[0];
      STEP(step_pl16, dlp1, 0, f1) f1 = pf[64];
      STEP(step_pl16, dlp0, 1, f2) f2 = pf[128];
      STEP(step_pl16, dlp1, 0, f3) f3 = pf[192];
      pf += 256;
    }
    float g0 = pf[0], g1 = pf[64], g2 = pf[128];  // rows 4093..4095
    STEP(step_pl16, dlp0, 1, f0)   // 4089
    STEP(step_pl16, dlp1, 0, f1)   // 4090
    STEP(step_pl16, dlp0, 1, f2)   // 4091
    STEP(step_pl16, dlp1, 0, f3)   // 4092
    STEP(step_pl16, dlp0, 1, g0)   // 4093
    STEP(step_pl16, dlp1, 0, g1)   // 4094
    STEP(step_pl16, dlp0, 1, g2)   // 4095
  } else
#endif
  {
    for (int it = 0; it < 1022; ++it) {
      STEP(step_shfl, dlp0, 1, f0) f0 = pf[0];
      STEP(step_shfl, dlp1, 0, f1) f1 = pf[64];
      STEP(step_shfl, dlp0, 1, f2) f2 = pf[128];
      STEP(step_shfl, dlp1, 0, f3) f3 = pf[192];
      pf += 256;
    }
    float g0 = pf[0], g1 = pf[64], g2 = pf[128];
    STEP(step_shfl, dlp0, 1, f0)
    STEP(step_shfl, dlp1, 0, f1)
    STEP(step_shfl, dlp0, 1, f2)
    STEP(step_shfl, dlp1, 0, f3)
    STEP(step_shfl, dlp0, 1, g0)
    STEP(step_shfl, dlp1, 0, g1)
    STEP(step_shfl, dlp0, 1, g2)
  }
#undef STEP
#undef LDS_BAR
}

// ---------------- K2: single-pass argmax backpointers (proven 216us) --------
// row r = t*128 + b; delta layout [T][B][L] makes row base = delta + r*64.
// Two contiguous halves scanned ascending with strict >, merge prefers lower
// half on tie = jnp.argmax first-occurrence. (Two-pass s[64] variant measured
// SLOWER: -10% instrs but occupancy cliff past 64-VGPR step, R24.)
__global__ __launch_bounds__(256) void psi_from_delta(const float* __restrict__ delta,
                                                      const float* __restrict__ trans,
                                                      unsigned char* __restrict__ psi) {
  const int lane = threadIdx.x & 63;
  const int w = __builtin_amdgcn_readfirstlane(blockIdx.x * 4 + (threadIdx.x >> 6));
  float tr[kL];
#pragma unroll
  for (int k = 0; k < kL; k += 4) {
    float4 v = *reinterpret_cast<const float4*>(trans + lane * kL + k);
    tr[k] = v.x; tr[k + 1] = v.y; tr[k + 2] = v.z; tr[k + 3] = v.w;
  }
  const int r0 = w * 8;  // 8 rows per wave; grid sized exactly
  for (int rr = 0; rr < 8; ++rr) {
    const int r = r0 + rr;
    const float4* row4 = reinterpret_cast<const float4*>(delta + (size_t)r * kL);
    float bA = -INFINITY, bBv = -INFINITY;
    int iA = 0, iB = 32;
#pragma unroll
    for (int q = 0; q < 8; ++q) {
      float4 dv = row4[q];
      float c; bool g;
      c = tr[4 * q + 0] + dv.x; g = c > bA; bA = g ? c : bA; iA = g ? 4 * q + 0 : iA;
      c = tr[4 * q + 1] + dv.y; g = c > bA; bA = g ? c : bA; iA = g ? 4 * q + 1 : iA;
      c = tr[4 * q + 2] + dv.z; g = c > bA; bA = g ? c : bA; iA = g ? 4 * q + 2 : iA;
      c = tr[4 * q + 3] + dv.w; g = c > bA; bA = g ? c : bA; iA = g ? 4 * q + 3 : iA;
    }
#pragma unroll
    for (int q = 8; q < 16; ++q) {
      float4 dv = row4[q];
      float c; bool g;
      c = tr[4 * q + 0] + dv.x; g = c > bBv; bBv = g ? c : bBv; iB = g ? 4 * q + 0 : iB;
      c = tr[4 * q + 1] + dv.y; g = c > bBv; bBv = g ? c : bBv; iB = g ? 4 * q + 1 : iB;
      c = tr[4 * q + 2] + dv.z; g = c > bBv; bBv = g ? c : bBv; iB = g ? 4 * q + 2 : iB;
      c = tr[4 * q + 3] + dv.w; g = c > bBv; bBv = g ? c : bBv; iB = g ? 4 * q + 3 : iB;
    }
    bool gm = bBv > bA;  // tie -> lower half (first occurrence)
    psi[(size_t)r * kL + lane] = (unsigned char)(gm ? iB : iA);
  }
}

// ---------------- K3: segment composition (in-place psi -> M) ----------------
__global__ __launch_bounds__(256) void seg_compose(unsigned char* psiM,
                                                   unsigned char* __restrict__ C) {
  const int lane = threadIdx.x & 63;
  const int w = blockIdx.x * 4 + (threadIdx.x >> 6);
  const int s = w >> 7;
  const int b = w & 127;
  const int tstart = s * kSegLen;
  const int tend = (tstart + kSegLen < kT) ? tstart + kSegLen : kT - 1;  // last seg: 4095
  const size_t stride = (size_t)kB * kL;
  size_t off = ((size_t)(tend - 1) * kB + b) * kL + lane;
  int m = lane;
  int v = psiM[off];
  for (int t = tend - 1; t > tstart; --t) {
    int vn = psiM[off - stride];          // prefetch next row
    m = __shfl(v, m, 64);                 // m = psi_row[m]
    psiM[off] = (unsigned char)m;         // M[t][b][e] = path[t] | hyp e
    v = vn;
    off -= stride;
  }
  m = __shfl(v, m, 64);
  psiM[off] = (unsigned char)m;
  C[((size_t)s * kB + b) * kL + lane] = (unsigned char)m;  // composed map
}

// ---------------- K4: score, last label, boundary-label scan ----------------
__global__ __launch_bounds__(64) void score_scan(const float* __restrict__ dfin,
                                                 const unsigned char* __restrict__ C,
                                                 int* __restrict__ E,
                                                 float* __restrict__ out) {
  const int b = blockIdx.x;
  const int i = threadIdx.x;
  float d = dfin[(size_t)b * kL + i];
  float m = d;
#pragma unroll
  for (int off = 32; off; off >>= 1) m = fmaxf(m, __shfl_xor(m, off, 64));
  unsigned long long msk = __ballot(d == m);
  int ll = __ffsll(msk) - 1;  // first (lowest) argmax lane
  if (i == 0) {
    out[b] = m;
    out[kB + (size_t)b * kT + (kT - 1)] = (float)ll;
    int lbl = ll;
    for (int s = kSeg - 1; s >= 0; --s) {
      E[s * kB + b] = lbl;                              // label at t_end(s)
      lbl = C[((size_t)s * kB + b) * kL + lbl];         // -> label at t_start(s)
    }
  }
}

// ---------------- K5: parallel path gather ----------------
__global__ __launch_bounds__(256) void path_fill(const unsigned char* __restrict__ M,
                                                 const int* __restrict__ E,
                                                 float* __restrict__ out) {
  const int n = blockIdx.x * 256 + threadIdx.x;  // n = b*4096 + t
  const int b = n >> 12;
  const int t = n & (kT - 1);
  if (t == kT - 1) return;  // written by score_scan
  const int e = E[(t >> 6) * kB + b];
  const unsigned char lab = M[((size_t)t * kB + b) * kL + e];
  out[kB + (size_t)b * kT + t] = (float)lab;
}

extern "C" void kernel_launch(void* const* d_in, const int* in_sizes, int n_in,
                              void* d_out, int out_size, void* d_ws, size_t ws_size,
                              hipStream_t stream) {
  const float* feats = (const float*)d_in[0];
  const float* trans = (const float*)d_in[1];
  float* out = (float*)d_out;
  char* ws = (char*)d_ws;

  const size_t deltaB = (size_t)kT * kB * kL * 4;   // 134,217,728
  const size_t psiB   = (size_t)kT * kB * kL;       //  33,554,432
  const size_t CBy    = (size_t)kSeg * kB * kL;     //     524,288

  float* delta = (float*)ws;
  unsigned char* psi = (unsigned char*)(ws + deltaB);
  unsigned char* C = (unsigned char*)(ws + deltaB + psiB);
  int* E = (int*)(ws + deltaB + psiB + CBy);
  hipLaunchKernelGGL(fwd_delta, dim3(kB), dim3(256), 0, stream, feats, trans, delta);
  hipLaunchKernelGGL(psi_from_delta, dim3(16380), dim3(256), 0, stream, delta, trans, psi);
  hipLaunchKernelGGL(seg_compose, dim3(2048), dim3(256), 0, stream, psi, C);
  hipLaunchKernelGGL(score_scan, dim3(kB), dim3(64), 0, stream,
                     delta + (size_t)(kT - 1) * kB * kL, C, E, out);
  hipLaunchKernelGGL(path_fill, dim3(2048), dim3(256), 0, stream, psi, E, out);
}